// Round 1
// baseline (41.218 us; speedup 1.0000x reference)
//
#include <hip/hip_runtime.h>

// out[i] = dot(ref_data[i,:], W[label[i],:])
// B = 8192 rows, D = 8192 cols, 10 experts.
// Memory-bound: 256 MiB ref_data read dominates. One block per row.

#define BLOCK 256
#define DDIM 8192

__global__ __launch_bounds__(BLOCK) void gather_dot_kernel(
    const float* __restrict__ X,      // [B, D]
    const int*   __restrict__ label,  // [B]
    const float* __restrict__ W,      // [10, D]
    float*       __restrict__ out)    // [B]
{
    const int row = blockIdx.x;
    const int e   = label[row];

    const float4* __restrict__ x =
        reinterpret_cast<const float4*>(X + (size_t)row * DDIM);
    const float4* __restrict__ w =
        reinterpret_cast<const float4*>(W + (size_t)e * DDIM);

    const int nvec = DDIM / 4;  // 2048 float4 per row

    float acc = 0.0f;
    #pragma unroll
    for (int k = 0; k < nvec / BLOCK; ++k) {          // 8 iterations
        const int i = threadIdx.x + k * BLOCK;        // coalesced 16B/lane
        float4 a = x[i];
        float4 b = w[i];
        acc = fmaf(a.x, b.x, acc);
        acc = fmaf(a.y, b.y, acc);
        acc = fmaf(a.z, b.z, acc);
        acc = fmaf(a.w, b.w, acc);
    }

    // wave-level butterfly reduce across 64 lanes
    #pragma unroll
    for (int off = 32; off > 0; off >>= 1)
        acc += __shfl_down(acc, off, 64);

    __shared__ float partial[BLOCK / 64];
    const int lane = threadIdx.x & 63;
    const int wid  = threadIdx.x >> 6;
    if (lane == 0) partial[wid] = acc;
    __syncthreads();

    if (threadIdx.x == 0) {
        out[row] = partial[0] + partial[1] + partial[2] + partial[3];
    }
}

extern "C" void kernel_launch(void* const* d_in, const int* in_sizes, int n_in,
                              void* d_out, int out_size, void* d_ws, size_t ws_size,
                              hipStream_t stream) {
    const float* X     = (const float*)d_in[0];  // ref_data [8192, 8192] f32
    const int*   label = (const int*)  d_in[1];  // label    [8192]       int
    const float* W     = (const float*)d_in[2];  // W        [10, 8192]   f32
    float*       out   = (float*)d_out;          // [8192] f32

    const int B = out_size;  // 8192 rows
    gather_dot_kernel<<<B, BLOCK, 0, stream>>>(X, label, W, out);
}